// Round 2
// baseline (856.754 us; speedup 1.0000x reference)
//
#include <hip/hip_runtime.h>
#include <hip/hip_bf16.h>
#include <stdint.h>
#include <stddef.h>

// Problem sizes (fixed by the reference)
#define B_SZ 512
#define S_SZ 64
#define E_SZ 512
#define H_SZ 1024
#define V_SZ 1024
#define C_SZ 1000

typedef __hip_bfloat16 bf16;
typedef __attribute__((ext_vector_type(8))) __bf16 bf16x8;
typedef __attribute__((ext_vector_type(4))) float f32x4;

// ---- workspace layout (bytes), total 76 MB ----
#define EMB_OFF   (0ull)          // emb_w bf16    [1024][512]  1 MB
#define WIH_OFF   (1ull << 20)    // w_ih  bf16    [1024][512]  1 MB
#define WHH_OFF   (2ull << 20)    // w_hh  bf16    [1024][1024] 2 MB
#define FC1_OFF   (4ull << 20)    // fc1_w bf16    [1024][1024] 2 MB
#define FC2_OFF   (6ull << 20)    // fc2_w bf16    [1024][1024] 2 MB (rows >=1000 zero)
#define H0_OFF    (8ull << 20)    // h buf 0 bf16  [512][1024]  1 MB
#define H1_OFF    (9ull << 20)    // h buf 1 bf16  [512][1024]  1 MB
#define YL_OFF    (10ull << 20)   // y_last bf16   [512][1024]  1 MB
#define Y1_OFF    (11ull << 20)   // fc1 out bf16  [512][1024]  1 MB
#define XP_OFF    (12ull << 20)   // x_proj bf16   [64][512][1024] 64 MB

// async global->LDS, 16B/lane. HW writes lane l at lds_base + l*16 (linear,
// wave-uniform base). Swizzled layouts are achieved by pre-swizzling the
// per-lane GLOBAL source address (rule #21: linear dest + inv-swz source +
// swz on read; XOR is its own inverse).
__device__ __forceinline__ void gl_lds16(const void* g, void* l) {
  __builtin_amdgcn_global_load_lds(
      (const __attribute__((address_space(1))) unsigned int*)g,
      (__attribute__((address_space(3))) unsigned int*)l, 16, 0, 0);
}

// ---------------------------------------------------------------------------
// prep: fp32 -> bf16 weight conversion + zero-init h0 + zero-pad fc2 rows
// ---------------------------------------------------------------------------
__global__ __launch_bounds__(256) void prep_kernel(
    const float* __restrict__ emb_w, const float* __restrict__ w_ih,
    const float* __restrict__ w_hh, const float* __restrict__ fc1_w,
    const float* __restrict__ fc2_w, char* __restrict__ ws) {
  bf16* emb = (bf16*)(ws + EMB_OFF);
  bf16* wih = (bf16*)(ws + WIH_OFF);
  bf16* whh = (bf16*)(ws + WHH_OFF);
  bf16* fc1 = (bf16*)(ws + FC1_OFF);
  bf16* fc2 = (bf16*)(ws + FC2_OFF);
  bf16* h0  = (bf16*)(ws + H0_OFF);

  const long N_EMB = 524288;   // 1024*512
  const long N_WIH = 524288;
  const long N_WHH = 1048576;  // 1024*1024
  const long N_FC1 = 1048576;
  const long N_FC2 = 1048576;  // padded to 1024 rows
  const long N_H0  = 524288;   // 512*1024
  const long TOTAL = N_EMB + N_WIH + N_WHH + N_FC1 + N_FC2 + N_H0;

  long stride = (long)gridDim.x * blockDim.x;
  for (long i = (long)blockIdx.x * blockDim.x + threadIdx.x; i < TOTAL; i += stride) {
    long j = i;
    if (j < N_EMB) { emb[j] = __float2bfloat16(emb_w[j]); continue; }
    j -= N_EMB;
    if (j < N_WIH) { wih[j] = __float2bfloat16(w_ih[j]); continue; }
    j -= N_WIH;
    if (j < N_WHH) { whh[j] = __float2bfloat16(w_hh[j]); continue; }
    j -= N_WHH;
    if (j < N_FC1) { fc1[j] = __float2bfloat16(fc1_w[j]); continue; }
    j -= N_FC1;
    if (j < N_FC2) {
      fc2[j] = (j < (long)C_SZ * H_SZ) ? __float2bfloat16(fc2_w[j]) : __float2bfloat16(0.f);
      continue;
    }
    j -= N_FC2;
    h0[j] = __float2bfloat16(0.f);
  }
}

// ---------------------------------------------------------------------------
// xproj: xp[s][b][h] = sum_e emb[x_in[b][s]][e] * w_ih[h][e] + b_ih[h]
// GEMM M=32768 (r=s*512+b), N=1024, K=512. Tile 128x128, BK=64, 4 waves,
// double-buffered LDS, XOR-swizzled (chunk^=row&7 in 8-bf16 units),
// embedding gather folded into per-lane staging source addresses.
// ---------------------------------------------------------------------------
__global__ __launch_bounds__(256) void xproj_kernel(
    const int* __restrict__ x_in, const float* __restrict__ b_ih,
    char* __restrict__ ws) {
  const bf16* emb = (const bf16*)(ws + EMB_OFF);
  const bf16* wih = (const bf16*)(ws + WIH_OFF);
  bf16* xp = (bf16*)(ws + XP_OFF);

  __shared__ bf16 Asm[2][128][64];  // 16 KB per buffer
  __shared__ bf16 Bsm[2][128][64];

  const int tid = threadIdx.x;
  const int lane = tid & 63;
  const int wid = tid >> 6;
  const int mb = blockIdx.x >> 3;  // 0..255
  const int nb = blockIdx.x & 7;   // 0..7
  const int rowBase = mb * 128;
  const int colBase = nb * 128;
  const int s = rowBase >> 9;      // whole 128-row tile shares one s

  // staging lane geometry for [*][64] tiles: 1KB = 8 rows of 128B
  const int lrow = lane >> 3;      // 0..7
  const int lchk = lane & 7;       // 0..7 (8 bf16 chunks)

  // tokens for this lane's 4 A-staging rows (row = wid*32 + i*8 + lrow)
  int tok[4];
#pragma unroll
  for (int i = 0; i < 4; ++i) {
    int rt = wid * 32 + i * 8 + lrow;
    int b = (rowBase + rt) & 511;
    tok[i] = x_in[b * S_SZ + s];
  }

  const int wr = wid >> 1, wc = wid & 1;
  f32x4 acc[4][4];
#pragma unroll
  for (int i = 0; i < 4; ++i)
#pragma unroll
    for (int j = 0; j < 4; ++j) acc[i][j] = (f32x4){0.f, 0.f, 0.f, 0.f};

  auto stage = [&](int buf, int k0) {
#pragma unroll
    for (int i = 0; i < 4; ++i) {
      int rt = wid * 32 + i * 8;                      // wave-uniform
      int sc = (lchk ^ ((rt + lrow) & 7)) * 8;        // inv-swizzled source
      gl_lds16(emb + (size_t)tok[i] * E_SZ + k0 + sc, &Asm[buf][rt][0]);
    }
#pragma unroll
    for (int i = 0; i < 4; ++i) {
      int rt = wid * 32 + i * 8;
      int sc = (lchk ^ ((rt + lrow) & 7)) * 8;
      gl_lds16(wih + (size_t)(colBase + rt + lrow) * E_SZ + k0 + sc, &Bsm[buf][rt][0]);
    }
  };

  stage(0, 0);
  __syncthreads();
  int cur = 0;
  for (int t8 = 0; t8 < 8; ++t8) {   // K = 8 * 64
    if (t8 < 7) stage(cur ^ 1, (t8 + 1) * 64);
#pragma unroll
    for (int kk = 0; kk < 2; ++kk) {
      const int kfc = kk * 4 + (lane >> 4);  // chunk index 0..7
      bf16x8 a[4], b[4];
#pragma unroll
      for (int i = 0; i < 4; ++i) {
        int r = wr * 64 + i * 16 + (lane & 15);
        a[i] = *(const bf16x8*)&Asm[cur][r][(kfc ^ (r & 7)) * 8];
      }
#pragma unroll
      for (int j = 0; j < 4; ++j) {
        int r = wc * 64 + j * 16 + (lane & 15);
        b[j] = *(const bf16x8*)&Bsm[cur][r][(kfc ^ (r & 7)) * 8];
      }
#pragma unroll
      for (int i = 0; i < 4; ++i)
#pragma unroll
        for (int j = 0; j < 4; ++j)
          acc[i][j] = __builtin_amdgcn_mfma_f32_16x16x32_bf16(a[i], b[j], acc[i][j], 0, 0, 0);
    }
    __syncthreads();  // implicit vmcnt(0)+lgkmcnt(0): dbuf safe w/ 1 barrier
    cur ^= 1;
  }

  // epilogue: D mapping col=lane&15, row=(lane>>4)*4+reg (m89-verified)
  const int crow = (lane >> 4) * 4;
  const int ccol = lane & 15;
#pragma unroll
  for (int j = 0; j < 4; ++j) {
    const int col = colBase + wc * 64 + j * 16 + ccol;
    const float bias = b_ih[col];
#pragma unroll
    for (int i = 0; i < 4; ++i) {
      const int r0 = rowBase + wr * 64 + i * 16 + crow;
#pragma unroll
      for (int reg = 0; reg < 4; ++reg) {
        float v = acc[i][j][reg] + bias;
        xp[(size_t)(r0 + reg) * H_SZ + col] = __float2bfloat16(v);
      }
    }
  }
}

// ---------------------------------------------------------------------------
// gemm32: M=512, N=1024, K=1024. Tile 32x64, BK=128, 4 waves (2x2 of 16x32),
// double-buffered + XOR-swizzled LDS. Grid 256 (one WG/CU).
// MODE 0: RNN step  h_out = tanh(A@B^T + xp_t + b_hh); capture y_last
// MODE 1: FC1       out = relu(A@B^T + b) -> bf16
// MODE 2: FC2       out = A@B^T + b -> fp32 (cols < 1000)
// ---------------------------------------------------------------------------
template <int MODE>
__global__ __launch_bounds__(256) void gemm32_kernel(
    const bf16* __restrict__ A, const bf16* __restrict__ Bw,
    const float* __restrict__ bias, const bf16* __restrict__ xp_t,
    const int* __restrict__ lens, int t,
    bf16* __restrict__ hout, bf16* __restrict__ yl,
    float* __restrict__ out_f32) {
  __shared__ bf16 Asm[2][32][128];  // 8 KB per buffer
  __shared__ bf16 Bsm[2][64][128];  // 16 KB per buffer

  const int tid = threadIdx.x;
  const int lane = tid & 63;
  const int wid = tid >> 6;
  const int mb = blockIdx.x >> 4;  // 0..15
  const int nb = blockIdx.x & 15;  // 0..15
  const int rowBase = mb * 32;
  const int colBase = nb * 64;
  const int wr = wid >> 1, wc = wid & 1;

  // staging lane geometry for [*][128] tiles: 1KB = 4 rows of 256B
  const int lrow = lane >> 4;      // 0..3
  const int lchk = lane & 15;      // 0..15 (8-bf16 chunks)

  f32x4 acc[2];
#pragma unroll
  for (int j = 0; j < 2; ++j) acc[j] = (f32x4){0.f, 0.f, 0.f, 0.f};

  auto stage = [&](int buf, int k0) {
#pragma unroll
    for (int i = 0; i < 2; ++i) {                      // A: 8 rows per wave
      int rt = wid * 8 + i * 4;                        // wave-uniform
      int sc = (lchk ^ ((rt + lrow) & 7)) * 8;         // inv-swizzled source
      gl_lds16(A + (size_t)(rowBase + rt + lrow) * H_SZ + k0 + sc, &Asm[buf][rt][0]);
    }
#pragma unroll
    for (int i = 0; i < 4; ++i) {                      // B: 16 rows per wave
      int rt = wid * 16 + i * 4;
      int sc = (lchk ^ ((rt + lrow) & 7)) * 8;
      gl_lds16(Bw + (size_t)(colBase + rt + lrow) * H_SZ + k0 + sc, &Bsm[buf][rt][0]);
    }
  };

  stage(0, 0);
  __syncthreads();
  int cur = 0;
  for (int t8 = 0; t8 < 8; ++t8) {   // K = 8 * 128
    if (t8 < 7) stage(cur ^ 1, (t8 + 1) * 128);
#pragma unroll
    for (int kc = 0; kc < 4; ++kc) {
      const int kfc = kc * 4 + (lane >> 4);  // chunk index 0..15
      const int ra = wr * 16 + (lane & 15);
      bf16x8 a = *(const bf16x8*)&Asm[cur][ra][(kfc ^ (ra & 7)) * 8];
#pragma unroll
      for (int j = 0; j < 2; ++j) {
        const int rb = wc * 32 + j * 16 + (lane & 15);
        bf16x8 b = *(const bf16x8*)&Bsm[cur][rb][(kfc ^ (rb & 7)) * 8];
        acc[j] = __builtin_amdgcn_mfma_f32_16x16x32_bf16(a, b, acc[j], 0, 0, 0);
      }
    }
    __syncthreads();
    cur ^= 1;
  }

  const int crow = (lane >> 4) * 4;
  const int ccol = lane & 15;
#pragma unroll
  for (int j = 0; j < 2; ++j) {
    const int col = colBase + wc * 32 + j * 16 + ccol;
    const float bv = (MODE == 2 && col >= C_SZ) ? 0.f : bias[col];
#pragma unroll
    for (int reg = 0; reg < 4; ++reg) {
      const int row = rowBase + wr * 16 + crow + reg;
      float v = acc[j][reg] + bv;
      if (MODE == 0) {
        v += __bfloat162float(xp_t[(size_t)row * H_SZ + col]);
        float h = tanhf(v);
        bf16 hb = __float2bfloat16(h);
        hout[(size_t)row * H_SZ + col] = hb;
        if (t == lens[row] - 1) yl[(size_t)row * H_SZ + col] = hb;
      } else if (MODE == 1) {
        v = fmaxf(v, 0.f);
        hout[(size_t)row * H_SZ + col] = __float2bfloat16(v);
      } else {
        if (col < C_SZ) out_f32[(size_t)row * C_SZ + col] = v;
      }
    }
  }
}

// ---------------------------------------------------------------------------
extern "C" void kernel_launch(void* const* d_in, const int* in_sizes, int n_in,
                              void* d_out, int out_size, void* d_ws, size_t ws_size,
                              hipStream_t stream) {
  (void)in_sizes; (void)n_in; (void)out_size; (void)ws_size;
  const int* x_in = (const int*)d_in[0];
  const int* x_len = (const int*)d_in[1];
  const float* emb_w = (const float*)d_in[2];
  const float* w_ih = (const float*)d_in[3];
  const float* b_ih = (const float*)d_in[4];
  const float* w_hh = (const float*)d_in[5];
  const float* b_hh = (const float*)d_in[6];
  const float* fc1_w = (const float*)d_in[7];
  const float* fc1_b = (const float*)d_in[8];
  const float* fc2_w = (const float*)d_in[9];
  const float* fc2_b = (const float*)d_in[10];
  char* ws = (char*)d_ws;
  float* out = (float*)d_out;

  // 1) weights -> bf16, zero h0, pad fc2
  prep_kernel<<<4608, 256, 0, stream>>>(emb_w, w_ih, w_hh, fc1_w, fc2_w, ws);

  // 2) x_proj GEMM (gathered A), [S*B, H]
  xproj_kernel<<<2048, 256, 0, stream>>>(x_in, b_ih, ws);

  // 3) 64 sequential RNN steps
  bf16* hb0 = (bf16*)(ws + H0_OFF);
  bf16* hb1 = (bf16*)(ws + H1_OFF);
  const bf16* whh = (const bf16*)(ws + WHH_OFF);
  const bf16* xp = (const bf16*)(ws + XP_OFF);
  bf16* yl = (bf16*)(ws + YL_OFF);
  for (int t = 0; t < S_SZ; ++t) {
    bf16* hin = (t & 1) ? hb1 : hb0;
    bf16* ho = (t & 1) ? hb0 : hb1;
    gemm32_kernel<0><<<256, 256, 0, stream>>>(
        hin, whh, b_hh, xp + (size_t)t * (B_SZ * H_SZ), x_len, t, ho, yl, nullptr);
  }

  // 4) FC1 (relu) then FC2
  gemm32_kernel<1><<<256, 256, 0, stream>>>(
      yl, (const bf16*)(ws + FC1_OFF), fc1_b, nullptr, nullptr, 0,
      (bf16*)(ws + Y1_OFF), nullptr, nullptr);
  gemm32_kernel<2><<<256, 256, 0, stream>>>(
      (const bf16*)(ws + Y1_OFF), (const bf16*)(ws + FC2_OFF), fc2_b, nullptr,
      nullptr, 0, nullptr, nullptr, out);
}